// Round 3
// baseline (241.252 us; speedup 1.0000x reference)
//
#include <hip/hip_runtime.h>

// MHA: D_MODEL=1024, D_K=64, H=16, N=2, T=2048. fp32 I/O, bf16 MFMA internals.
// R13b: flash_attn VALU diet (R13 resubmit; __exp2f collided with glibc's
// reserved name -> use __builtin_amdgcn_exp2f = raw v_exp_f32).
// R12 counters: VALUBusy 54% (top pipe), MfmaUtil 19%, HBM 13.5%, grid-capped
// occupancy (1024 blocks = 4/CU exactly). Two VALU cuts:
//  1) exp2 fold: gemm_qkv scales Q by 0.125*log2(e); flash uses native
//     v_exp_f32 via __builtin_amdgcn_exp2f -> saves 16 v_mul/wave-tile.
//  2) packed mask bits: transposeW packs mask (2x2048 int) into 64 uint64
//     via __ballot, stored in the dead q-fp32 buffer (d_in[1], dead after
//     convert3; stream-ordered). flash loads one wave-uniform uint64 per
//     tile + uniform branch: all-ones -> no per-value mask work at all;
//     else bit-extract slow path. Kills 4 redundant int4 global loads per
//     lane per tile (halves vmem issue count) + 16 cndmask.
// vmcnt ledger per iter is now V x2, K(t+1) x2: vmcnt(4) before QK drains
// K(t); vmcnt(2) before softmax drains V(t), K(t+1) stays in flight.
// gemm_qkv/gemm_out/convert3 structure unchanged from R12.
// ws >= 32MB: bf16 k,q,v + 4 transposed bf16 weights. Intermediates in dead
// fp32 input buffers. XOR-swizzled LDS everywhere (conflict-free + DMA-legal).

typedef __bf16 bf16;
typedef __bf16 bf16x8 __attribute__((ext_vector_type(8)));
typedef __bf16 bf16x4 __attribute__((ext_vector_type(4)));
typedef float f32x4 __attribute__((ext_vector_type(4)));

#define MFMA16(a, b, c) __builtin_amdgcn_mfma_f32_16x16x32_bf16((a), (b), (c), 0, 0, 0)
#define EXP2(x) __builtin_amdgcn_exp2f(x)

__device__ __forceinline__ void load_lds16(const bf16* g, bf16* l) {
  __builtin_amdgcn_global_load_lds(
      (const __attribute__((address_space(1))) unsigned int*)g,
      (__attribute__((address_space(3))) unsigned int*)l, 16, 0, 0);
}

__device__ __forceinline__ bf16x8 cvt8(const float* __restrict__ p) {
  const f32x4 a = *(const f32x4*)p;
  const f32x4 b = *(const f32x4*)(p + 4);
  bf16x8 r;
  r[0] = (bf16)a[0]; r[1] = (bf16)a[1]; r[2] = (bf16)a[2]; r[3] = (bf16)a[3];
  r[4] = (bf16)b[0]; r[5] = (bf16)b[1]; r[6] = (bf16)b[2]; r[7] = (bf16)b[3];
  return r;
}

// ---------------------------------------------------------------------------
// Prepass 1: k,q,v (4M fp32 each) -> bf16.
// ---------------------------------------------------------------------------
__global__ __launch_bounds__(256) void convert3(const float* __restrict__ a,
                                                const float* __restrict__ b,
                                                const float* __restrict__ c,
                                                bf16* __restrict__ oa,
                                                bf16* __restrict__ ob,
                                                bf16* __restrict__ oc) {
  const size_t i = ((size_t)blockIdx.x * 256 + threadIdx.x) * 8;
  const int which = (int)(i >> 22);
  const size_t off = i & ((size_t)(1u << 22) - 1);
  const float* src = which == 0 ? a : (which == 1 ? b : c);
  bf16* dst = which == 0 ? oa : (which == 1 ? ob : oc);
  *(bf16x8*)&dst[off] = cvt8(&src[off]);
}

// ---------------------------------------------------------------------------
// Prepass 2: W [1024k x 1024n] fp32 -> WT [n][k] bf16. grid (16,16,4).
// Side duty (blocks x=0,y=0, waves 0-1): pack mask into 64 uint64 tiles.
// ---------------------------------------------------------------------------
__global__ __launch_bounds__(256) void transposeW(
    const float* __restrict__ W0, const float* __restrict__ W1,
    const float* __restrict__ W2, const float* __restrict__ W3,
    bf16* __restrict__ T0, bf16* __restrict__ T1, bf16* __restrict__ T2,
    bf16* __restrict__ T3, const int* __restrict__ mask,
    unsigned long long* __restrict__ mbits) {
  __shared__ bf16 t[64 * 72];
  const int z = blockIdx.z;
  const float* W = z == 0 ? W0 : (z == 1 ? W1 : (z == 2 ? W2 : W3));
  bf16* T = z == 0 ? T0 : (z == 1 ? T1 : (z == 2 ? T2 : T3));
  const int kBase = blockIdx.y * 64, nBase = blockIdx.x * 64;
  const int tid = threadIdx.x;
  const int row = tid >> 2, cs = (tid & 3) * 16;

  const float* src = &W[(size_t)(kBase + row) * 1024 + nBase + cs];
  *(bf16x8*)&t[row * 72 + cs] = cvt8(src);
  *(bf16x8*)&t[row * 72 + cs + 8] = cvt8(src + 8);
  __syncthreads();

  const int n = tid >> 2, ks = (tid & 3) * 16;
  bf16 buf[16];
#pragma unroll
  for (int j = 0; j < 16; ++j) buf[j] = t[(ks + j) * 72 + n];
  bf16* dst = &T[(size_t)(nBase + n) * 1024 + kBase + ks];
  *(bf16x8*)&dst[0] = *(bf16x8*)&buf[0];
  *(bf16x8*)&dst[8] = *(bf16x8*)&buf[8];

  // maskpack: 64 tiles of 64 keys -> one uint64 each (bit i = key i live).
  // Spread over the 4 z-blocks (x=0,y=0), 2 waves each, 8 tiles per wave.
  if (blockIdx.x == 0 && blockIdx.y == 0 && tid < 128) {
    const int w = tid >> 6, lane = tid & 63;
#pragma unroll
    for (int i = 0; i < 8; ++i) {
      const int tile = z * 16 + w * 8 + i;
      const unsigned long long bits = __ballot(mask[tile * 64 + lane] != 0);
      if (lane == 0) mbits[tile] = bits;
    }
  }
}

// ---------------------------------------------------------------------------
// gemm_qkv: fused K/V/Q projections. BM=128, BN=64 (one head per block),
// BK=64; 4 waves, wave tile 64x32 (4x2 acc, 16 MFMA/iter); 24KB LDS ->
// 6 blocks/CU; grid (16,32,3) = 1536 blocks.
// z=0: K (bh,t,d). z=1: Vt (bh,d,t) via LDS transpose. z=2: Q, *0.125*log2e
// (log2e folded so flash can use native exp2).
// ---------------------------------------------------------------------------
__global__ __launch_bounds__(256) void gemm_qkv(
    const bf16* __restrict__ kb, const bf16* __restrict__ vb,
    const bf16* __restrict__ qb, const bf16* __restrict__ WkT,
    const bf16* __restrict__ WvT, const bf16* __restrict__ WqT,
    const float* __restrict__ bk, const float* __restrict__ bv,
    const float* __restrict__ bq, bf16* __restrict__ K_buf,
    bf16* __restrict__ Vt_buf, bf16* __restrict__ Q_buf) {
  // S: As = [0, 8192) [m][k], Ws = [8192, 12288) [n][k]. 24 KB.
  __shared__ __align__(16) bf16 S[12288];
  bf16* As = S;
  bf16* Ws = S + 8192;
  const int tid = threadIdx.x;
  const int lane = tid & 63, w = tid >> 6;
  const int l15 = lane & 15, quad = lane >> 4;
  const int z = blockIdx.z;
  const bf16* X = z == 0 ? kb : (z == 1 ? vb : qb);
  const bf16* WT = z == 0 ? WkT : (z == 1 ? WvT : WqT);
  const float* B = z == 0 ? bk : (z == 1 ? bv : bq);
  const int mBase = blockIdx.y * 128, nBase = blockIdx.x * 64;
  const int wm = (w >> 1) * 64, wn = (w & 1) * 32;

  const int r8 = tid >> 3;                    // 0..31
  const int jg = ((tid & 7) ^ (r8 & 7)) * 8;  // swizzled col seg
  const int sw = l15 & 7;

  f32x4 acc[4][2] = {};

  for (int k0 = 0; k0 < 1024; k0 += 64) {
    __syncthreads();
#pragma unroll
    for (int i = 0; i < 4; ++i)
      load_lds16(&X[(size_t)(mBase + r8 + i * 32) * 1024 + k0 + jg],
                 &As[(tid + i * 256) * 8]);
#pragma unroll
    for (int i = 0; i < 2; ++i)
      load_lds16(&WT[(size_t)(nBase + r8 + i * 32) * 1024 + k0 + jg],
                 &Ws[(tid + i * 256) * 8]);
    __syncthreads();

#pragma unroll
    for (int k2 = 0; k2 < 2; ++k2) {
      const int col = ((k2 * 4 + quad) ^ sw) * 8;
      bf16x8 a[4], bb[2];
#pragma unroll
      for (int mt = 0; mt < 4; ++mt)
        a[mt] = *(const bf16x8*)&As[(wm + mt * 16 + l15) * 64 + col];
#pragma unroll
      for (int nt = 0; nt < 2; ++nt)
        bb[nt] = *(const bf16x8*)&Ws[(wn + nt * 16 + l15) * 64 + col];
#pragma unroll
      for (int mt = 0; mt < 4; ++mt)
#pragma unroll
        for (int nt = 0; nt < 2; ++nt)
          acc[mt][nt] = MFMA16(a[mt], bb[nt], acc[mt][nt]);
    }
  }

  // Epilogue. C layout: col = l15 (n-local), row = quad*4+r (m-local).
  const int h = nBase >> 6;  // BN=64: one head per block
  if (z != 1) {
    // 0.125 * log2(e): flash uses exp2(s) == e^(q.k/8)
    const float scale = (z == 2) ? 0.18033688011112042f : 1.0f;
    bf16* o = (z == 0) ? K_buf : Q_buf;
#pragma unroll
    for (int nt = 0; nt < 2; ++nt) {
      const int n = nBase + wn + nt * 16 + l15;
      const float bias = B[n];
      const int d = n & 63;
#pragma unroll
      for (int mt = 0; mt < 4; ++mt)
#pragma unroll
        for (int r = 0; r < 4; ++r) {
          const int m = mBase + wm + mt * 16 + quad * 4 + r;
          const int b = m >> 11, t = m & 2047;
          o[((size_t)(b * 16 + h) * 2048 + t) * 64 + d] =
              (bf16)((acc[mt][nt][r] + bias) * scale);
        }
    }
  } else {
    // Vt: transpose each wave's 64(t)x32(d) C-tile in LDS, store b128 along t.
    __syncthreads();  // frag reads of S done
    bf16* Tb = &S[w * 2304];  // 32 x 72
#pragma unroll
    for (int nt = 0; nt < 2; ++nt) {
      const int n = nBase + wn + nt * 16 + l15;
      const float bias = B[n];
#pragma unroll
      for (int mt = 0; mt < 4; ++mt) {
        bf16x4 pk;
#pragma unroll
        for (int r = 0; r < 4; ++r) pk[r] = (bf16)(acc[mt][nt][r] + bias);
        *(bf16x4*)&Tb[(nt * 16 + l15) * 72 + mt * 16 + quad * 4] = pk;
      }
    }
    // same-wave in-order LDS: no barrier needed
    const int b = mBase >> 11;  // 128-row tile never straddles batch
#pragma unroll
    for (int i = 0; i < 4; ++i) {
      const int dl = i * 8 + (lane >> 3), ts = (lane & 7) * 8;
      const bf16x8 vv = *(const bf16x8*)&Tb[dl * 72 + ts];
      const int d = wn + dl;
      const int t = (mBase + wm + ts) & 2047;
      *(bf16x8*)&Vt_buf[((size_t)(b * 16 + h) * 64 + d) * 2048 + t] = vv;
    }
  }
}

// ---------------------------------------------------------------------------
// gemm_out (R9 exact): out = A @ WoT^T + bo -> fp32. BM=128, BN=64, BK=64.
// ---------------------------------------------------------------------------
__global__ __launch_bounds__(256) void gemm_out(const bf16* __restrict__ X,
                                                const bf16* __restrict__ WT,
                                                const float* __restrict__ B,
                                                float* __restrict__ out) {
  __shared__ __align__(16) bf16 As[128 * 64];
  __shared__ __align__(16) bf16 Ws[64 * 64];
  const int tid = threadIdx.x;
  const int lane = tid & 63, w = tid >> 6;
  const int l15 = lane & 15, quad = lane >> 4;
  const int mBase = blockIdx.y * 128, nBase = blockIdx.x * 64;
  const int wm = (w >> 1) * 64, wn = (w & 1) * 32;

  const int r8 = tid >> 3;
  const int jg = ((tid & 7) ^ (r8 & 7)) * 8;
  const int sw = l15 & 7;

  f32x4 acc[4][2] = {};

  for (int k0 = 0; k0 < 1024; k0 += 64) {
    __syncthreads();
#pragma unroll
    for (int i = 0; i < 4; ++i)
      load_lds16(&X[(size_t)(mBase + r8 + i * 32) * 1024 + k0 + jg],
                 &As[(tid + i * 256) * 8]);
#pragma unroll
    for (int i = 0; i < 2; ++i)
      load_lds16(&WT[(size_t)(nBase + r8 + i * 32) * 1024 + k0 + jg],
                 &Ws[(tid + i * 256) * 8]);
    __syncthreads();

#pragma unroll
    for (int k2 = 0; k2 < 2; ++k2) {
      const int col = ((k2 * 4 + quad) ^ sw) * 8;
      bf16x8 a[4], bb[2];
#pragma unroll
      for (int mt = 0; mt < 4; ++mt)
        a[mt] = *(const bf16x8*)&As[(wm + mt * 16 + l15) * 64 + col];
#pragma unroll
      for (int nt = 0; nt < 2; ++nt)
        bb[nt] = *(const bf16x8*)&Ws[(wn + nt * 16 + l15) * 64 + col];
#pragma unroll
      for (int mt = 0; mt < 4; ++mt)
#pragma unroll
        for (int nt = 0; nt < 2; ++nt)
          acc[mt][nt] = MFMA16(a[mt], bb[nt], acc[mt][nt]);
    }
  }

#pragma unroll
  for (int nt = 0; nt < 2; ++nt) {
    const int n = nBase + wn + nt * 16 + l15;
    const float bias = B[n];
#pragma unroll
    for (int mt = 0; mt < 4; ++mt)
#pragma unroll
      for (int r = 0; r < 4; ++r) {
        const int m = mBase + wm + mt * 16 + quad * 4 + r;
        out[(size_t)m * 1024 + n] = acc[mt][nt][r] + bias;
      }
  }
}

// ---------------------------------------------------------------------------
// flash_attn (R13b): S^T/O^T form, fixed-reference softmax (m=0), per-lane
// scalar row sum. K double-buffered, counted vmcnt, raw s_barrier, setprio.
// Mask via per-tile uint64 (wave-uniform scalar load) + uniform fast path.
// vmcnt ledger per iter (issue order): V(t) x2, K(t+1) x2.
//   - vmcnt(4) before QK  -> drains K(t)   (issued one iter earlier: free)
//   - vmcnt(2) before SM  -> drains V(t), K(t+1) stays in flight
// ---------------------------------------------------------------------------
__global__ __launch_bounds__(256) void flash_attn(
    const bf16* __restrict__ Q, const bf16* __restrict__ K,
    const bf16* __restrict__ Vt, const unsigned long long* __restrict__ mbits,
    bf16* __restrict__ A) {
  __shared__ __align__(16) bf16 Ks[2][64 * 64];  // [key][d] swizzled, dbuf
  __shared__ __align__(16) bf16 Vs[64 * 64];     // [d][key] swizzled
  __shared__ __align__(16) bf16 Ps[64 * 72];     // [q][key], wave-private rows

  const int tid = threadIdx.x;
  const int lane = tid & 63, w = tid >> 6;
  const int l15 = lane & 15, quad = lane >> 4;
  const int bh = blockIdx.y;
  const int b = bh >> 4, h = bh & 15;
  const int qt = blockIdx.x * 64;

  const int r8 = tid >> 3;
  const int jg = ((tid & 7) ^ (r8 & 7)) * 8;
  const int sw = l15 & 7;

  const size_t qbase = ((size_t)bh * 2048 + qt + w * 16 + l15) * 64;
  const bf16x8 bq0 = *(const bf16x8*)&Q[qbase + quad * 8];
  const bf16x8 bq1 = *(const bf16x8*)&Q[qbase + 32 + quad * 8];

  f32x4 o[4] = {};
  float rs = 0.0f;

  // Prologue: K(0) -> Ks[0]. Outstanding: 2 (matches steady state).
#pragma unroll
  for (int i = 0; i < 2; ++i)
    load_lds16(&K[((size_t)bh * 2048 + r8 + i * 32) * 64 + jg],
               &Ks[0][(tid + i * 256) * 8]);

  int cur = 0;
  for (int kt = 0; kt < 2048; kt += 64) {
    // barrier[1]: PV(t-1) done everywhere -> Vs free; QK(t-1) done -> Ks[cur^1] free.
    __builtin_amdgcn_s_barrier();

    // Wave-uniform mask word for this tile (scalar load; latency hidden).
    const unsigned long long mb = mbits[b * 32 + (kt >> 6)];

    // Issue V(t) -> Vs (vmcnt +2)
#pragma unroll
    for (int i = 0; i < 2; ++i)
      load_lds16(&Vt[((size_t)bh * 64 + r8 + i * 32) * 2048 + kt + jg],
                 &Vs[(tid + i * 256) * 8]);
    // Issue K(t+1) -> Ks[cur^1] (vmcnt +2). Last iter wraps to tile 0 into the
    // dead buffer: keeps the vmcnt ledger uniform, never read.
    const int ktn = (kt + 64) & 2047;
#pragma unroll
    for (int i = 0; i < 2; ++i)
      load_lds16(&K[((size_t)bh * 2048 + ktn + r8 + i * 32) * 64 + jg],
                 &Ks[cur ^ 1][(tid + i * 256) * 8]);

    // K(t) arrived (4 newer ops outstanding); make it visible block-wide.
    asm volatile("s_waitcnt vmcnt(4)" ::: "memory");
    __builtin_amdgcn_s_barrier();  // barrier[2]

    // QK^T on Ks[cur]
    const bf16* Kc = Ks[cur];
    f32x4 s4[4];
    __builtin_amdgcn_s_setprio(1);
#pragma unroll
    for (int nt = 0; nt < 4; ++nt) {
      const bf16x8 ak0 = *(const bf16x8*)&Kc[(nt * 16 + l15) * 64 + ((quad ^ sw) * 8)];
      const bf16x8 ak1 = *(const bf16x8*)&Kc[(nt * 16 + l15) * 64 + (((4 + quad) ^ sw) * 8)];
      f32x4 s = {};
      s = MFMA16(ak0, bq0, s);
      s = MFMA16(ak1, bq1, s);
      s4[nt] = s;
    }
    __builtin_amdgcn_s_setprio(0);

    // V(t) arrived; K(t+1) stays in flight across the next barrier.
    asm volatile("s_waitcnt vmcnt(2)" ::: "memory");

    // Softmax -> Ps (rows wave-private, DS in-order per wave: no barrier).
    // Q carries log2(e): p = exp2(s) = e^(q.k/8). Uniform fast path when the
    // tile's 64 mask bits are all set (no per-value mask work at all).
    if (mb + 1ull == 0ull) {
#pragma unroll
      for (int nt = 0; nt < 4; ++nt) {
        const float p0 = EXP2(s4[nt][0]);
        const float p1 = EXP2(s4[nt][1]);
        const float p2 = EXP2(s4[nt][2]);
        const float p3 = EXP2(s4[nt][3]);
        rs += (p0 + p1) + (p2 + p3);
        bf16x4 pk;
        pk[0] = (bf16)p0; pk[1] = (bf16)p1; pk[2] = (bf16)p2; pk[3] = (bf16)p3;
        *(bf16x4*)&Ps[(w * 16 + l15) * 72 + nt * 16 + quad * 4] = pk;
      }
    } else {
#pragma unroll
      for (int nt = 0; nt < 4; ++nt) {
        const unsigned g = (unsigned)(mb >> (nt * 16)) & 0xffffu;  // scalar
        const int bp = quad * 4;                                   // per-lane
        const float p0 = ((g >> (bp + 0)) & 1u) ? EXP2(s4[nt][0]) : 0.0f;
        const float p1 = ((g >> (bp + 1)) & 1u) ? EXP2(s4[nt][1]) : 0.0f;
        const float p2 = ((g >> (bp + 2)) & 1u) ? EXP2(s4[nt][2]) : 0.0f;
        const float p3 = ((g >> (bp + 3)) & 1u) ? EXP2(s4[nt][3]) : 0.0f;
        rs += (p0 + p1) + (p2 + p3);
        bf16x4 pk;
        pk[0] = (bf16)p0; pk[1] = (bf16)p1; pk[2] = (bf16)p2; pk[3] = (bf16)p3;
        *(bf16x4*)&Ps[(w * 16 + l15) * 72 + nt * 16 + quad * 4] = pk;
      }
    }

    __builtin_amdgcn_s_barrier();  // barrier[3]: everyone's V(t) drained -> Vs visible

    __builtin_amdgcn_s_setprio(1);
#pragma unroll
    for (int ks = 0; ks < 2; ++ks) {
      const bf16x8 bp = *(const bf16x8*)&Ps[(w * 16 + l15) * 72 + ks * 32 + quad * 8];
#pragma unroll
      for (int mt = 0; mt < 4; ++mt) {
        const bf16x8 av =
            *(const bf16x8*)&Vs[(mt * 16 + l15) * 64 + (((ks * 4 + quad) ^ sw) * 8)];
        o[mt] = MFMA16(av, bp, o[mt]);
      }
    }
    __builtin_amdgcn_s_setprio(0);

    cur ^= 1;
  }

  rs += __shfl_xor(rs, 16);
  rs += __shfl_xor(rs, 32);
  const float inv = rs > 0.0f ? 1.0f / rs : 0.0f;

  const int t = qt + w * 16 + l15;
  const size_t base = ((size_t)b * 2048 + t) * 1024 + h * 64;
#pragma unroll
  for (int mt = 0; mt < 4; ++mt) {
    bf16x4 ov;
#pragma unroll
    for (int r = 0; r < 4; ++r) ov[r] = (bf16)(o[mt][r] * inv);
    *(bf16x4*)&A[base + mt * 16 + quad * 4] = ov;
  }
}

// ---------------------------------------------------------------------------
extern "C" void kernel_launch(void* const* d_in, const int* in_sizes, int n_in,
                              void* d_out, int out_size, void* d_ws, size_t ws_size,
                              hipStream_t stream) {
  const float* k = (const float*)d_in[0];
  const float* q = (const float*)d_in[1];
  const float* v = (const float*)d_in[2];
  const int* mask = (const int*)d_in[3];
  const float* Wk = (const float*)d_in[4];
  const float* bk = (const float*)d_in[5];
  const float* Wq = (const float*)d_in[6];
  const float* bq = (const float*)d_in[7];
  const float* Wv = (const float*)d_in[8];
  const float* bv = (const float*)d_in[9];
  const float* Wo = (const float*)d_in[10];
  const float* bo = (const float*)d_in[11];

  const size_t ELEMS = (size_t)4 * 1024 * 1024;
  const size_t WELEMS = (size_t)1024 * 1024;

  bf16* kb = (bf16*)d_ws;
  bf16* qb = kb + ELEMS;
  bf16* vb = qb + ELEMS;
  bf16* WkT = vb + ELEMS;
  bf16* WqT = WkT + WELEMS;
  bf16* WvT = WqT + WELEMS;
  bf16* WoT = WvT + WELEMS;

  bf16* K_buf = (bf16*)d_in[0];
  bf16* Q_buf = (bf16*)d_in[0] + ELEMS;
  bf16* Vt_buf = (bf16*)d_in[2];
  bf16* A_buf = (bf16*)d_in[2] + ELEMS;
  // q fp32 (d_in[1]) is dead after convert3; transposeW (stream-ordered
  // after it) parks the 64 packed mask words there for flash_attn.
  unsigned long long* mbits = (unsigned long long*)d_in[1];

  convert3<<<6144, 256, 0, stream>>>(k, q, v, kb, qb, vb);
  transposeW<<<dim3(16, 16, 4), 256, 0, stream>>>(Wk, Wq, Wv, Wo,
                                                  WkT, WqT, WvT, WoT,
                                                  mask, mbits);
  gemm_qkv<<<dim3(16, 32, 3), 256, 0, stream>>>(kb, vb, qb, WkT, WvT, WqT,
                                                bk, bv, bq, K_buf, Vt_buf, Q_buf);
  flash_attn<<<dim3(32, 32), 256, 0, stream>>>(Q_buf, K_buf, Vt_buf, mbits, A_buf);
  gemm_out<<<dim3(16, 32), 256, 0, stream>>>(A_buf, WoT, bo, (float*)d_out);
}

// Round 4
// 225.259 us; speedup vs baseline: 1.0710x; 1.0710x over previous
//
#include <hip/hip_runtime.h>

// MHA: D_MODEL=1024, D_K=64, H=16, N=2, T=2048. fp32 I/O, bf16 MFMA internals.
// R14: flash_attn LDS-bandwidth fix. R13b counters: VALUBusy 36, MfmaUtil 22,
// HBM 16% -- no pipe saturated, but LDS budget per CU-iter (16 waves x 18
// ds_read_b128 x ~12cyc + Ps writes + 128KB staging DMA) = ~4900 cyc vs
// measured 4600-cyc iteration wall => LDS-pipe-bound. K/V fragment reads are
// replicated per wave; amortize by doubling Q per wave: each wave handles
// 32 q-rows (two 16-q B-frags), block = 128 q (4 waves), grid 512 = 2/CU.
// Same 8 K-frag + 8 V-frag reads now feed 2x MFMA; staging DMA per CU halves.
// LDS budget drops ~4900 -> ~2850 cyc/CU-iter. LDS 42KB/block, VGPR ~105.
// Pipeline (R12) kept: K dbuf, counted vmcnt (V x2, K x2: vmcnt(4)/vmcnt(2)),
// raw s_barrier, setprio. Mask via packed uint64 + uniform fast path (R13b).
// exp2 fold: Q pre-scaled by 0.125*log2(e), flash uses raw v_exp_f32.
// gemm_qkv/gemm_out/convert3/transposeW unchanged from R13b.
// ws >= 32MB: bf16 k,q,v + 4 transposed bf16 weights. Intermediates in dead
// fp32 input buffers. XOR-swizzled LDS everywhere (conflict-free + DMA-legal).

typedef __bf16 bf16;
typedef __bf16 bf16x8 __attribute__((ext_vector_type(8)));
typedef __bf16 bf16x4 __attribute__((ext_vector_type(4)));
typedef float f32x4 __attribute__((ext_vector_type(4)));

#define MFMA16(a, b, c) __builtin_amdgcn_mfma_f32_16x16x32_bf16((a), (b), (c), 0, 0, 0)
#define EXP2(x) __builtin_amdgcn_exp2f(x)

__device__ __forceinline__ void load_lds16(const bf16* g, bf16* l) {
  __builtin_amdgcn_global_load_lds(
      (const __attribute__((address_space(1))) unsigned int*)g,
      (__attribute__((address_space(3))) unsigned int*)l, 16, 0, 0);
}

__device__ __forceinline__ bf16x8 cvt8(const float* __restrict__ p) {
  const f32x4 a = *(const f32x4*)p;
  const f32x4 b = *(const f32x4*)(p + 4);
  bf16x8 r;
  r[0] = (bf16)a[0]; r[1] = (bf16)a[1]; r[2] = (bf16)a[2]; r[3] = (bf16)a[3];
  r[4] = (bf16)b[0]; r[5] = (bf16)b[1]; r[6] = (bf16)b[2]; r[7] = (bf16)b[3];
  return r;
}

// ---------------------------------------------------------------------------
// Prepass 1: k,q,v (4M fp32 each) -> bf16.
// ---------------------------------------------------------------------------
__global__ __launch_bounds__(256) void convert3(const float* __restrict__ a,
                                                const float* __restrict__ b,
                                                const float* __restrict__ c,
                                                bf16* __restrict__ oa,
                                                bf16* __restrict__ ob,
                                                bf16* __restrict__ oc) {
  const size_t i = ((size_t)blockIdx.x * 256 + threadIdx.x) * 8;
  const int which = (int)(i >> 22);
  const size_t off = i & ((size_t)(1u << 22) - 1);
  const float* src = which == 0 ? a : (which == 1 ? b : c);
  bf16* dst = which == 0 ? oa : (which == 1 ? ob : oc);
  *(bf16x8*)&dst[off] = cvt8(&src[off]);
}

// ---------------------------------------------------------------------------
// Prepass 2: W [1024k x 1024n] fp32 -> WT [n][k] bf16. grid (16,16,4).
// Side duty (blocks x=0,y=0, waves 0-1): pack mask into 64 uint64 tiles.
// ---------------------------------------------------------------------------
__global__ __launch_bounds__(256) void transposeW(
    const float* __restrict__ W0, const float* __restrict__ W1,
    const float* __restrict__ W2, const float* __restrict__ W3,
    bf16* __restrict__ T0, bf16* __restrict__ T1, bf16* __restrict__ T2,
    bf16* __restrict__ T3, const int* __restrict__ mask,
    unsigned long long* __restrict__ mbits) {
  __shared__ bf16 t[64 * 72];
  const int z = blockIdx.z;
  const float* W = z == 0 ? W0 : (z == 1 ? W1 : (z == 2 ? W2 : W3));
  bf16* T = z == 0 ? T0 : (z == 1 ? T1 : (z == 2 ? T2 : T3));
  const int kBase = blockIdx.y * 64, nBase = blockIdx.x * 64;
  const int tid = threadIdx.x;
  const int row = tid >> 2, cs = (tid & 3) * 16;

  const float* src = &W[(size_t)(kBase + row) * 1024 + nBase + cs];
  *(bf16x8*)&t[row * 72 + cs] = cvt8(src);
  *(bf16x8*)&t[row * 72 + cs + 8] = cvt8(src + 8);
  __syncthreads();

  const int n = tid >> 2, ks = (tid & 3) * 16;
  bf16 buf[16];
#pragma unroll
  for (int j = 0; j < 16; ++j) buf[j] = t[(ks + j) * 72 + n];
  bf16* dst = &T[(size_t)(nBase + n) * 1024 + kBase + ks];
  *(bf16x8*)&dst[0] = *(bf16x8*)&buf[0];
  *(bf16x8*)&dst[8] = *(bf16x8*)&buf[8];

  // maskpack: 64 tiles of 64 keys -> one uint64 each (bit i = key i live).
  if (blockIdx.x == 0 && blockIdx.y == 0 && tid < 128) {
    const int w = tid >> 6, lane = tid & 63;
#pragma unroll
    for (int i = 0; i < 8; ++i) {
      const int tile = z * 16 + w * 8 + i;
      const unsigned long long bits = __ballot(mask[tile * 64 + lane] != 0);
      if (lane == 0) mbits[tile] = bits;
    }
  }
}

// ---------------------------------------------------------------------------
// gemm_qkv: fused K/V/Q projections. BM=128, BN=64 (one head per block),
// BK=64; 4 waves, wave tile 64x32 (4x2 acc, 16 MFMA/iter); 24KB LDS ->
// 6 blocks/CU; grid (16,32,3) = 1536 blocks.
// z=0: K (bh,t,d). z=1: Vt (bh,d,t) via LDS transpose. z=2: Q, *0.125*log2e.
// ---------------------------------------------------------------------------
__global__ __launch_bounds__(256) void gemm_qkv(
    const bf16* __restrict__ kb, const bf16* __restrict__ vb,
    const bf16* __restrict__ qb, const bf16* __restrict__ WkT,
    const bf16* __restrict__ WvT, const bf16* __restrict__ WqT,
    const float* __restrict__ bk, const float* __restrict__ bv,
    const float* __restrict__ bq, bf16* __restrict__ K_buf,
    bf16* __restrict__ Vt_buf, bf16* __restrict__ Q_buf) {
  __shared__ __align__(16) bf16 S[12288];
  bf16* As = S;
  bf16* Ws = S + 8192;
  const int tid = threadIdx.x;
  const int lane = tid & 63, w = tid >> 6;
  const int l15 = lane & 15, quad = lane >> 4;
  const int z = blockIdx.z;
  const bf16* X = z == 0 ? kb : (z == 1 ? vb : qb);
  const bf16* WT = z == 0 ? WkT : (z == 1 ? WvT : WqT);
  const float* B = z == 0 ? bk : (z == 1 ? bv : bq);
  const int mBase = blockIdx.y * 128, nBase = blockIdx.x * 64;
  const int wm = (w >> 1) * 64, wn = (w & 1) * 32;

  const int r8 = tid >> 3;
  const int jg = ((tid & 7) ^ (r8 & 7)) * 8;
  const int sw = l15 & 7;

  f32x4 acc[4][2] = {};

  for (int k0 = 0; k0 < 1024; k0 += 64) {
    __syncthreads();
#pragma unroll
    for (int i = 0; i < 4; ++i)
      load_lds16(&X[(size_t)(mBase + r8 + i * 32) * 1024 + k0 + jg],
                 &As[(tid + i * 256) * 8]);
#pragma unroll
    for (int i = 0; i < 2; ++i)
      load_lds16(&WT[(size_t)(nBase + r8 + i * 32) * 1024 + k0 + jg],
                 &Ws[(tid + i * 256) * 8]);
    __syncthreads();

#pragma unroll
    for (int k2 = 0; k2 < 2; ++k2) {
      const int col = ((k2 * 4 + quad) ^ sw) * 8;
      bf16x8 a[4], bb[2];
#pragma unroll
      for (int mt = 0; mt < 4; ++mt)
        a[mt] = *(const bf16x8*)&As[(wm + mt * 16 + l15) * 64 + col];
#pragma unroll
      for (int nt = 0; nt < 2; ++nt)
        bb[nt] = *(const bf16x8*)&Ws[(wn + nt * 16 + l15) * 64 + col];
#pragma unroll
      for (int mt = 0; mt < 4; ++mt)
#pragma unroll
        for (int nt = 0; nt < 2; ++nt)
          acc[mt][nt] = MFMA16(a[mt], bb[nt], acc[mt][nt]);
    }
  }

  const int h = nBase >> 6;
  if (z != 1) {
    // 0.125 * log2(e): flash uses exp2(s) == e^(q.k/8)
    const float scale = (z == 2) ? 0.18033688011112042f : 1.0f;
    bf16* o = (z == 0) ? K_buf : Q_buf;
#pragma unroll
    for (int nt = 0; nt < 2; ++nt) {
      const int n = nBase + wn + nt * 16 + l15;
      const float bias = B[n];
      const int d = n & 63;
#pragma unroll
      for (int mt = 0; mt < 4; ++mt)
#pragma unroll
        for (int r = 0; r < 4; ++r) {
          const int m = mBase + wm + mt * 16 + quad * 4 + r;
          const int b = m >> 11, t = m & 2047;
          o[((size_t)(b * 16 + h) * 2048 + t) * 64 + d] =
              (bf16)((acc[mt][nt][r] + bias) * scale);
        }
    }
  } else {
    __syncthreads();
    bf16* Tb = &S[w * 2304];  // 32 x 72
#pragma unroll
    for (int nt = 0; nt < 2; ++nt) {
      const int n = nBase + wn + nt * 16 + l15;
      const float bias = B[n];
#pragma unroll
      for (int mt = 0; mt < 4; ++mt) {
        bf16x4 pk;
#pragma unroll
        for (int r = 0; r < 4; ++r) pk[r] = (bf16)(acc[mt][nt][r] + bias);
        *(bf16x4*)&Tb[(nt * 16 + l15) * 72 + mt * 16 + quad * 4] = pk;
      }
    }
    const int b = mBase >> 11;
#pragma unroll
    for (int i = 0; i < 4; ++i) {
      const int dl = i * 8 + (lane >> 3), ts = (lane & 7) * 8;
      const bf16x8 vv = *(const bf16x8*)&Tb[dl * 72 + ts];
      const int d = wn + dl;
      const int t = (mBase + wm + ts) & 2047;
      *(bf16x8*)&Vt_buf[((size_t)(b * 16 + h) * 64 + d) * 2048 + t] = vv;
    }
  }
}

// ---------------------------------------------------------------------------
// gemm_out (R9 exact): out = A @ WoT^T + bo -> fp32. BM=128, BN=64, BK=64.
// ---------------------------------------------------------------------------
__global__ __launch_bounds__(256) void gemm_out(const bf16* __restrict__ X,
                                                const bf16* __restrict__ WT,
                                                const float* __restrict__ B,
                                                float* __restrict__ out) {
  __shared__ __align__(16) bf16 As[128 * 64];
  __shared__ __align__(16) bf16 Ws[64 * 64];
  const int tid = threadIdx.x;
  const int lane = tid & 63, w = tid >> 6;
  const int l15 = lane & 15, quad = lane >> 4;
  const int mBase = blockIdx.y * 128, nBase = blockIdx.x * 64;
  const int wm = (w >> 1) * 64, wn = (w & 1) * 32;

  const int r8 = tid >> 3;
  const int jg = ((tid & 7) ^ (r8 & 7)) * 8;
  const int sw = l15 & 7;

  f32x4 acc[4][2] = {};

  for (int k0 = 0; k0 < 1024; k0 += 64) {
    __syncthreads();
#pragma unroll
    for (int i = 0; i < 4; ++i)
      load_lds16(&X[(size_t)(mBase + r8 + i * 32) * 1024 + k0 + jg],
                 &As[(tid + i * 256) * 8]);
#pragma unroll
    for (int i = 0; i < 2; ++i)
      load_lds16(&WT[(size_t)(nBase + r8 + i * 32) * 1024 + k0 + jg],
                 &Ws[(tid + i * 256) * 8]);
    __syncthreads();

#pragma unroll
    for (int k2 = 0; k2 < 2; ++k2) {
      const int col = ((k2 * 4 + quad) ^ sw) * 8;
      bf16x8 a[4], bb[2];
#pragma unroll
      for (int mt = 0; mt < 4; ++mt)
        a[mt] = *(const bf16x8*)&As[(wm + mt * 16 + l15) * 64 + col];
#pragma unroll
      for (int nt = 0; nt < 2; ++nt)
        bb[nt] = *(const bf16x8*)&Ws[(wn + nt * 16 + l15) * 64 + col];
#pragma unroll
      for (int mt = 0; mt < 4; ++mt)
#pragma unroll
        for (int nt = 0; nt < 2; ++nt)
          acc[mt][nt] = MFMA16(a[mt], bb[nt], acc[mt][nt]);
    }
  }

#pragma unroll
  for (int nt = 0; nt < 2; ++nt) {
    const int n = nBase + wn + nt * 16 + l15;
    const float bias = B[n];
#pragma unroll
    for (int mt = 0; mt < 4; ++mt)
#pragma unroll
      for (int r = 0; r < 4; ++r) {
        const int m = mBase + wm + mt * 16 + quad * 4 + r;
        out[(size_t)m * 1024 + n] = acc[mt][nt][r] + bias;
      }
  }
}

// ---------------------------------------------------------------------------
// flash_attn (R14): 128 q-rows/block (4 waves x 32 q each: two 16-q B-frags
// per wave sharing the K/V fragment reads). Grid (16,32) = 512 blocks = 2/CU.
// S^T/O^T form, fixed-reference softmax (m=0), per-lane scalar row sums.
// K dbuf, counted vmcnt (V x2, K x2 per iter): vmcnt(4) before QK drains
// K(t); vmcnt(2) before softmax drains V(t), K(t+1) in flight across barrier.
// ---------------------------------------------------------------------------
__global__ __launch_bounds__(256) void flash_attn(
    const bf16* __restrict__ Q, const bf16* __restrict__ K,
    const bf16* __restrict__ Vt, const unsigned long long* __restrict__ mbits,
    bf16* __restrict__ A) {
  __shared__ __align__(16) bf16 Ks[2][64 * 64];  // [key][d] swizzled, dbuf 16KB
  __shared__ __align__(16) bf16 Vs[64 * 64];     // [d][key] swizzled 8KB
  __shared__ __align__(16) bf16 Ps[128 * 72];    // [q][key], wave-private 18KB

  const int tid = threadIdx.x;
  const int lane = tid & 63, w = tid >> 6;
  const int l15 = lane & 15, quad = lane >> 4;
  const int bh = blockIdx.y;
  const int b = bh >> 4, h = bh & 15;
  const int qt = blockIdx.x * 128;

  const int r8 = tid >> 3;
  const int jg = ((tid & 7) ^ (r8 & 7)) * 8;
  const int sw = l15 & 7;

  // Two q-sets per wave: A = qt + w*32 + l15, B = A + 16.
  const size_t qbaseA = ((size_t)bh * 2048 + qt + w * 32 + l15) * 64;
  const size_t qbaseB = qbaseA + (size_t)16 * 64;
  const bf16x8 qA0 = *(const bf16x8*)&Q[qbaseA + quad * 8];
  const bf16x8 qA1 = *(const bf16x8*)&Q[qbaseA + 32 + quad * 8];
  const bf16x8 qB0 = *(const bf16x8*)&Q[qbaseB + quad * 8];
  const bf16x8 qB1 = *(const bf16x8*)&Q[qbaseB + 32 + quad * 8];

  f32x4 oA[4] = {}, oB[4] = {};
  float rsA = 0.0f, rsB = 0.0f;

  const int rowA = (w * 32 + l15) * 72;      // Ps row base, set A
  const int rowB = (w * 32 + 16 + l15) * 72; // set B

  // Prologue: K(0) -> Ks[0]. Outstanding: 2 (matches steady state).
#pragma unroll
  for (int i = 0; i < 2; ++i)
    load_lds16(&K[((size_t)bh * 2048 + r8 + i * 32) * 64 + jg],
               &Ks[0][(tid + i * 256) * 8]);

  int cur = 0;
  for (int kt = 0; kt < 2048; kt += 64) {
    // barrier[1]: PV(t-1) done -> Vs free; QK(t-1) done -> Ks[cur^1] free.
    __builtin_amdgcn_s_barrier();

    const unsigned long long mb = mbits[b * 32 + (kt >> 6)];

    // Issue V(t) -> Vs (vmcnt +2)
#pragma unroll
    for (int i = 0; i < 2; ++i)
      load_lds16(&Vt[((size_t)bh * 64 + r8 + i * 32) * 2048 + kt + jg],
                 &Vs[(tid + i * 256) * 8]);
    // Issue K(t+1) -> Ks[cur^1] (vmcnt +2); last iter wraps into dead buffer.
    const int ktn = (kt + 64) & 2047;
#pragma unroll
    for (int i = 0; i < 2; ++i)
      load_lds16(&K[((size_t)bh * 2048 + ktn + r8 + i * 32) * 64 + jg],
                 &Ks[cur ^ 1][(tid + i * 256) * 8]);

    // K(t) arrived (4 newer ops outstanding); make it visible block-wide.
    asm volatile("s_waitcnt vmcnt(4)" ::: "memory");
    __builtin_amdgcn_s_barrier();  // barrier[2]

    // QK^T on Ks[cur]: 8 K-frag reads shared by both q-sets (16 MFMA).
    const bf16* Kc = Ks[cur];
    f32x4 sA[4], sB[4];
    __builtin_amdgcn_s_setprio(1);
#pragma unroll
    for (int nt = 0; nt < 4; ++nt) {
      const bf16x8 ak0 = *(const bf16x8*)&Kc[(nt * 16 + l15) * 64 + ((quad ^ sw) * 8)];
      const bf16x8 ak1 = *(const bf16x8*)&Kc[(nt * 16 + l15) * 64 + (((4 + quad) ^ sw) * 8)];
      f32x4 s = {};
      s = MFMA16(ak0, qA0, s);
      s = MFMA16(ak1, qA1, s);
      sA[nt] = s;
      f32x4 t = {};
      t = MFMA16(ak0, qB0, t);
      t = MFMA16(ak1, qB1, t);
      sB[nt] = t;
    }
    __builtin_amdgcn_s_setprio(0);

    // V(t) arrived; K(t+1) stays in flight across the next barrier.
    asm volatile("s_waitcnt vmcnt(2)" ::: "memory");

    // Softmax -> Ps (rows wave-private, DS in-order per wave: no barrier).
    if (mb + 1ull == 0ull) {
#pragma unroll
      for (int nt = 0; nt < 4; ++nt) {
        const float a0 = EXP2(sA[nt][0]), a1 = EXP2(sA[nt][1]);
        const float a2 = EXP2(sA[nt][2]), a3 = EXP2(sA[nt][3]);
        rsA += (a0 + a1) + (a2 + a3);
        bf16x4 pa;
        pa[0] = (bf16)a0; pa[1] = (bf16)a1; pa[2] = (bf16)a2; pa[3] = (bf16)a3;
        *(bf16x4*)&Ps[rowA + nt * 16 + quad * 4] = pa;
        const float b0 = EXP2(sB[nt][0]), b1 = EXP2(sB[nt][1]);
        const float b2 = EXP2(sB[nt][2]), b3 = EXP2(sB[nt][3]);
        rsB += (b0 + b1) + (b2 + b3);
        bf16x4 pb;
        pb[0] = (bf16)b0; pb[1] = (bf16)b1; pb[2] = (bf16)b2; pb[3] = (bf16)b3;
        *(bf16x4*)&Ps[rowB + nt * 16 + quad * 4] = pb;
      }
    } else {
#pragma unroll
      for (int nt = 0; nt < 4; ++nt) {
        const unsigned g = (unsigned)(mb >> (nt * 16)) & 0xffffu;  // scalar
        const int bp = quad * 4;                                   // per-lane
        const unsigned m0 = (g >> (bp + 0)) & 1u, m1 = (g >> (bp + 1)) & 1u;
        const unsigned m2 = (g >> (bp + 2)) & 1u, m3 = (g >> (bp + 3)) & 1u;
        const float a0 = m0 ? EXP2(sA[nt][0]) : 0.0f;
        const float a1 = m1 ? EXP2(sA[nt][1]) : 0.0f;
        const float a2 = m2 ? EXP2(sA[nt][2]) : 0.0f;
        const float a3 = m3 ? EXP2(sA[nt][3]) : 0.0f;
        rsA += (a0 + a1) + (a2 + a3);
        bf16x4 pa;
        pa[0] = (bf16)a0; pa[1] = (bf16)a1; pa[2] = (bf16)a2; pa[3] = (bf16)a3;
        *(bf16x4*)&Ps[rowA + nt * 16 + quad * 4] = pa;
        const float b0 = m0 ? EXP2(sB[nt][0]) : 0.0f;
        const float b1 = m1 ? EXP2(sB[nt][1]) : 0.0f;
        const float b2 = m2 ? EXP2(sB[nt][2]) : 0.0f;
        const float b3 = m3 ? EXP2(sB[nt][3]) : 0.0f;
        rsB += (b0 + b1) + (b2 + b3);
        bf16x4 pb;
        pb[0] = (bf16)b0; pb[1] = (bf16)b1; pb[2] = (bf16)b2; pb[3] = (bf16)b3;
        *(bf16x4*)&Ps[rowB + nt * 16 + quad * 4] = pb;
      }
    }

    __builtin_amdgcn_s_barrier();  // barrier[3]: everyone's V(t) drained -> Vs visible

    // PV: 8 V-frag reads shared by both q-sets (16 MFMA), 4 Ps reads.
    __builtin_amdgcn_s_setprio(1);
#pragma unroll
    for (int ks = 0; ks < 2; ++ks) {
      const bf16x8 bpA = *(const bf16x8*)&Ps[rowA + ks * 32 + quad * 8];
      const bf16x8 bpB = *(const bf16x8*)&Ps[rowB + ks * 32 + quad * 8];
#pragma unroll
      for (int mt = 0; mt < 4; ++mt) {
        const bf16x8 av =
            *(const bf16x8*)&Vs[(mt * 16 + l15) * 64 + (((ks * 4 + quad) ^ sw) * 8)];
        oA[mt] = MFMA16(av, bpA, oA[mt]);
        oB[mt] = MFMA16(av, bpB, oB[mt]);
      }
    }
    __builtin_amdgcn_s_setprio(0);

    cur ^= 1;
  }

  rsA += __shfl_xor(rsA, 16);
  rsA += __shfl_xor(rsA, 32);
  rsB += __shfl_xor(rsB, 16);
  rsB += __shfl_xor(rsB, 32);
  const float invA = rsA > 0.0f ? 1.0f / rsA : 0.0f;
  const float invB = rsB > 0.0f ? 1.0f / rsB : 0.0f;

  const int tA = qt + w * 32 + l15;
  const size_t baseA = ((size_t)b * 2048 + tA) * 1024 + h * 64;
  const size_t baseB = baseA + (size_t)16 * 1024;
#pragma unroll
  for (int mt = 0; mt < 4; ++mt) {
    bf16x4 ovA, ovB;
#pragma unroll
    for (int r = 0; r < 4; ++r) {
      ovA[r] = (bf16)(oA[mt][r] * invA);
      ovB[r] = (bf16)(oB[mt][r] * invB);
    }
    *(bf16x4*)&A[baseA + mt * 16 + quad * 4] = ovA;
    *(bf16x4*)&A[baseB + mt * 16 + quad * 4] = ovB;
  }
}

// ---------------------------------------------------------------------------
extern "C" void kernel_launch(void* const* d_in, const int* in_sizes, int n_in,
                              void* d_out, int out_size, void* d_ws, size_t ws_size,
                              hipStream_t stream) {
  const float* k = (const float*)d_in[0];
  const float* q = (const float*)d_in[1];
  const float* v = (const float*)d_in[2];
  const int* mask = (const int*)d_in[3];
  const float* Wk = (const float*)d_in[4];
  const float* bk = (const float*)d_in[5];
  const float* Wq = (const float*)d_in[6];
  const float* bq = (const float*)d_in[7];
  const float* Wv = (const float*)d_in[8];
  const float* bv = (const float*)d_in[9];
  const float* Wo = (const float*)d_in[10];
  const float* bo = (const float*)d_in[11];

  const size_t ELEMS = (size_t)4 * 1024 * 1024;
  const size_t WELEMS = (size_t)1024 * 1024;

  bf16* kb = (bf16*)d_ws;
  bf16* qb = kb + ELEMS;
  bf16* vb = qb + ELEMS;
  bf16* WkT = vb + ELEMS;
  bf16* WqT = WkT + WELEMS;
  bf16* WvT = WqT + WELEMS;
  bf16* WoT = WvT + WELEMS;

  bf16* K_buf = (bf16*)d_in[0];
  bf16* Q_buf = (bf16*)d_in[0] + ELEMS;
  bf16* Vt_buf = (bf16*)d_in[2];
  bf16* A_buf = (bf16*)d_in[2] + ELEMS;
  // q fp32 (d_in[1]) is dead after convert3; transposeW (stream-ordered
  // after it) parks the 64 packed mask words there for flash_attn.
  unsigned long long* mbits = (unsigned long long*)d_in[1];

  convert3<<<6144, 256, 0, stream>>>(k, q, v, kb, qb, vb);
  transposeW<<<dim3(16, 16, 4), 256, 0, stream>>>(Wk, Wq, Wv, Wo,
                                                  WkT, WqT, WvT, WoT,
                                                  mask, mbits);
  gemm_qkv<<<dim3(16, 32, 3), 256, 0, stream>>>(kb, vb, qb, WkT, WvT, WqT,
                                                bk, bv, bq, K_buf, Vt_buf, Q_buf);
  flash_attn<<<dim3(16, 32), 256, 0, stream>>>(Q_buf, K_buf, Vt_buf, mbits, A_buf);
  gemm_out<<<dim3(16, 32), 256, 0, stream>>>(A_buf, WoT, bo, (float*)d_out);
}